// Round 4
// baseline (98.579 us; speedup 1.0000x reference)
//
#include <hip/hip_runtime.h>
#include <math.h>

#define TPB 256
#define CH  16            // samples per chunk
#define CPB 4             // chunks per block

static constexpr int B_     = 64;
static constexpr int S_     = 2048;
static constexpr int TOTAL  = B_ * S_;          // 131072 samples
static constexpr int NCHUNK = TOTAL / CH;       // 8192
static constexpr int NBLK   = NCHUNK / CPB;     // 2048 blocks (= 8/CU exactly)
static constexpr int SAMPB  = 600;              // bytes per sample (150 f32)
static constexpr int JF     = (CH + 2) * 150;   // 2700 floats (pred + 2 halo)
static constexpr int TFN    = CH * 150;         // 2400 floats (tgt)
static constexpr int TOFFB  = JF * 4;           // 10800 B: tgt region start in LDS
static constexpr int CHB    = TOFFB + TFN * 4;  // 20400 B staged per chunk
static constexpr long TOTB  = (long)TOTAL * SAMPB;

// ---- union bone table: 51 edges covers bone-set(49) + conn-set(49) ----
// k=9,10 conn-only -> sentinel ranges; k=7,8 bone-only -> wsup=0.
// k>=11 (hand edges): min=0.01, max=0.08, wsup=1 computed in code — NO long
// initializer rows (R3 failed from a silently-truncated 51-entry table).
__constant__ int US_[51] = {0,1,1,2,3,5,6,4,7,7,4,
    8,8,8,8,8,9,10,11,13,14,
    15,17,18,19,21,22,23,25,26,27,
    29,29,29,29,29,30,31,32,34,35,
    36,38,39,40,42,43,44,46,47,48};
__constant__ int UE_[51] = {1,2,5,3,4,6,7,8,29,8,29,
    9,13,17,21,25,10,11,12,14,15,
    16,18,19,20,22,23,24,26,27,28,
    30,34,38,42,46,31,32,33,35,36,
    37,39,40,41,43,44,45,47,48,49};
__constant__ float UMIN11_[11] = {0.05f,0.1f,0.1f,0.2f,0.2f,0.2f,0.2f,0.05f,0.05f,-1e9f,-1e9f};
__constant__ float UMAX11_[11] = {0.15f,0.2f,0.2f,0.35f,0.35f,0.35f,0.35f,0.15f,0.15f,1e9f,1e9f};
__constant__ float WSUP11_[11] = {1.f,1.f,1.f,1.f,1.f,1.f,1.f,0.f,0.f,1.f,1.f};
__constant__ int SL_[24] = {8,9,10,11,12,13,14,15,16,17,18,19,20,21,22,23,24,25,26,27,28,2,3,4};
__constant__ int SR_[24] = {29,30,31,32,33,34,35,36,37,38,39,40,41,42,43,44,45,46,47,48,49,5,6,7};
__constant__ int AJ_[4] = {1,1,2,5};
__constant__ int BJ_[4] = {2,5,3,6};
__constant__ int CJ_[4] = {3,6,4,7};

struct F3 { float x, y, z; };
__device__ __forceinline__ F3 ld3(const float* p) { return *(const F3*)p; }

__global__ __launch_bounds__(TPB, 5) void pose_main(
    const float* __restrict__ pred, const float* __restrict__ tgt,
    float* __restrict__ part)
{
    __shared__ __align__(16) float LDSBUF[JF + TFN];   // 20400 B
    float* Jl = LDSBUF;
    float* Tl = LDSBUF + JF;

    const int tid = threadIdx.x;
    const int blk = blockIdx.x;
    const int li  = tid & 15;
    const int g   = tid >> 4;
    const int jb  = li * 150;

    // ================= hoisted per-thread constants =================
    // union slots 0..2 : k = g + 16s  (k in 0..47)
    int   uS[3], uE[3];
    float uMn[3], uMx[3], uW[3];
    #pragma unroll
    for (int s = 0; s < 3; ++s) {
        const int k = g + 16 * s;
        uS[s] = jb + US_[k] * 3;  uE[s] = jb + UE_[k] * 3;
        uMn[s] = (k < 11) ? UMIN11_[k] : 0.01f;
        uMx[s] = (k < 11) ? UMAX11_[k] : 0.08f;
        uW[s]  = (k < 11) ? WSUP11_[k] : 1.f;
    }
    // extra union slot on wave3 (g=12,13,14 -> k=48,49,50; g=15 neutral)
    const int t3 = g - 12;
    const int ke = 48 + (t3 < 0 ? 0 : (t3 > 2 ? 2 : t3));
    const bool e_on = (g >= 12 && g < 15);
    const int   eS = jb + US_[ke] * 3, eE = jb + UE_[ke] * 3;
    const float eMn = e_on ? 0.01f : -1e9f;   // k>=48 are hand edges
    const float eMx = e_on ? 0.08f :  1e9f;
    const float eW  = e_on ? 1.f   :  0.f;
    // symmetry: slot0 k=g (all); slot1 k=16+(g-4) on waves 1,2
    const int s0L = jb + SL_[g] * 3, s0R = jb + SR_[g] * 3;
    const int k1  = 16 + ((g - 4) & 7);
    const int s1L = jb + SL_[k1] * 3, s1R = jb + SR_[k1] * 3;
    // angle: wave0, k = g (0..3)
    const int aA = jb + AJ_[g & 3] * 3, aB = jb + BJ_[g & 3] * 3, aC = jb + CJ_[g & 3] * 3;
    // temporal: base j = g (+48-float compile-time offsets for j=g+16,g+32)
    const int tb0 = jb + 3 * g;
    const int jx  = 48 + ((g - 4) & 1);          // wave1 extra: g=4->48, g=5->49
    const int tbx = jb + 3 * (jx > 49 ? 49 : jx);
    const bool tex_on = (g == 4 || g == 5);

    float a_bone = 0.f, a_ang = 0.f, a_sym = 0.f, a_vel = 0.f, a_acc = 0.f, a_sup = 0.f;

    // ================= T14 split staging =================
    float4 stg[5];
    auto issue = [&](int cidx) {
        const long nb = (long)cidx * (CH * SAMPB);
        const char* pb_ = (const char*)pred + nb;
        const char* tb_ = (const char*)tgt + nb - TOFFB;
        const long prem = TOTB - nb - 16;        // clamp halo at buffer end
        #pragma unroll
        for (int s = 0; s < 5; ++s) {
            const int o = tid * 16 + s * 4096;
            if (o < CHB) {
                if (o < TOFFB) {
                    long oc = o; if (oc > prem) oc = prem;
                    stg[s] = *(const float4*)(pb_ + oc);
                } else {
                    stg[s] = *(const float4*)(tb_ + o);
                }
            }
        }
    };
    auto commit = [&]() {
        #pragma unroll
        for (int s = 0; s < 5; ++s) {
            const int o = tid * 16 + s * 4096;
            if (o < CHB) *(float4*)((char*)LDSBUF + o) = stg[s];
        }
    };

    issue(blk * CPB);
    for (int c = 0; c < CPB; ++c) {
        const int cidx = blk * CPB + c;
        __syncthreads();                 // all waves done reading LDS (prev chunk)
        commit();                        // write staged chunk to LDS
        if (c + 1 < CPB) issue(cidx + 1);// prefetch next under this chunk's compute
        __syncthreads();

        // ---------- union: bone penalty + supervised ----------
        #pragma unroll
        for (int s = 0; s < 3; ++s) {
            const F3 je = ld3(Jl + uE[s]), js = ld3(Jl + uS[s]);
            const float dx = je.x - js.x, dy = je.y - js.y, dz = je.z - js.z;
            const float pb = sqrtf(dx * dx + dy * dy + dz * dz);
            a_bone += fmaxf(pb - uMx[s], 0.f) + fmaxf(uMn[s] - pb, 0.f);
            const F3 te = ld3(Tl + uE[s]), ts = ld3(Tl + uS[s]);
            const float tx = te.x - ts.x, ty = te.y - ts.y, tz = te.z - ts.z;
            const float tb = sqrtf(tx * tx + ty * ty + tz * tz);
            a_sup += uW[s] * fabsf(pb - tb);
        }
        if (tid >= 192) {   // wave3: union extra k=48..50
            const F3 je = ld3(Jl + eE), js = ld3(Jl + eS);
            const float dx = je.x - js.x, dy = je.y - js.y, dz = je.z - js.z;
            const float pb = sqrtf(dx * dx + dy * dy + dz * dz);
            a_bone += fmaxf(pb - eMx, 0.f) + fmaxf(eMn - pb, 0.f);
            const F3 te = ld3(Tl + eE), ts = ld3(Tl + eS);
            const float tx = te.x - ts.x, ty = te.y - ts.y, tz = te.z - ts.z;
            const float tb = sqrtf(tx * tx + ty * ty + tz * tz);
            a_sup += eW * fabsf(pb - tb);
        }

        // ---------- symmetry ----------
        {
            const F3 L = ld3(Jl + s0L), R = ld3(Jl + s0R);
            a_sym += fabsf(L.x + R.x) + 0.5f * (fabsf(L.y - R.y) + fabsf(L.z - R.z));
        }
        if (tid >= 64 && tid < 192) {   // waves 1,2: sym k=16..23
            const F3 L = ld3(Jl + s1L), R = ld3(Jl + s1R);
            a_sym += fabsf(L.x + R.x) + 0.5f * (fabsf(L.y - R.y) + fabsf(L.z - R.z));
        }

        // ---------- angles (wave0 only) ----------
        if (tid < 64) {
            const F3 A = ld3(Jl + aA), Bb = ld3(Jl + aB), C = ld3(Jl + aC);
            const float v1x = A.x - Bb.x, v1y = A.y - Bb.y, v1z = A.z - Bb.z;
            const float v2x = C.x - Bb.x, v2y = C.y - Bb.y, v2z = C.z - Bb.z;
            const float n12 = (v1x*v1x + v1y*v1y + v1z*v1z) * (v2x*v2x + v2y*v2y + v2z*v2z);
            const float inv = __frsqrt_rn(fmaxf(n12, 1e-24f));
            float cosv = (v1x*v2x + v1y*v2y + v1z*v2z) * inv;
            cosv = fminf(fmaxf(cosv, -1.f), 1.f);
            const float deg = acosf(cosv) * 57.29577951308232f;
            a_ang += fmaxf(30.f - deg, 0.f) + fmaxf(deg - 150.f, 0.f);
        }

        // ---------- temporal ----------
        {
            const int sidx = ((cidx * CH) & (S_ - 1)) + li;
            const bool v_ok = sidx < S_ - 1;
            const bool a_ok = sidx < S_ - 2;
            const float* tp = Jl + tb0;
            #pragma unroll
            for (int s = 0; s < 3; ++s) {
                const F3 p0 = ld3(tp + 48*s), p1 = ld3(tp + 48*s + 150), p2 = ld3(tp + 48*s + 300);
                if (v_ok) {
                    const float vx = p1.x - p0.x, vy = p1.y - p0.y, vz = p1.z - p0.z;
                    a_vel += sqrtf(vx*vx + vy*vy + vz*vz);
                    if (a_ok) {
                        const float ax = p2.x - 2.f*p1.x + p0.x;
                        const float ay = p2.y - 2.f*p1.y + p0.y;
                        const float az = p2.z - 2.f*p1.z + p0.z;
                        a_acc += sqrtf(ax*ax + ay*ay + az*az);
                    }
                }
            }
            if (tid >= 64 && tid < 128) {   // wave1 extra j=48,49
                const float* tq = Jl + tbx;
                const F3 p0 = ld3(tq), p1 = ld3(tq + 150), p2 = ld3(tq + 300);
                if (tex_on && v_ok) {
                    const float vx = p1.x - p0.x, vy = p1.y - p0.y, vz = p1.z - p0.z;
                    a_vel += sqrtf(vx*vx + vy*vy + vz*vz);
                    if (a_ok) {
                        const float ax = p2.x - 2.f*p1.x + p0.x;
                        const float ay = p2.y - 2.f*p1.y + p0.y;
                        const float az = p2.z - 2.f*p1.z + p0.z;
                        a_acc += sqrtf(ax*ax + ay*ay + az*az);
                    }
                }
            }
        }
    }

    // ================= block reduction =================
    float vals[6] = {a_bone, a_ang, a_sym, a_vel, a_acc, a_sup};
    #pragma unroll
    for (int k = 0; k < 6; ++k)
        #pragma unroll
        for (int off = 32; off > 0; off >>= 1)
            vals[k] += __shfl_down(vals[k], off, 64);

    __syncthreads();                     // safe to reuse LDS
    const int wid = tid >> 6, lane = tid & 63;
    if (lane == 0) {
        #pragma unroll
        for (int k = 0; k < 6; ++k) LDSBUF[wid * 6 + k] = vals[k];
    }
    __syncthreads();
    if (tid == 0) {
        #pragma unroll
        for (int k = 0; k < 6; ++k)     // SoA partials: part[k][blk]
            part[k * NBLK + blk] = LDSBUF[k] + LDSBUF[6 + k] + LDSBUF[12 + k] + LDSBUF[18 + k];
    }
}

__global__ __launch_bounds__(256) void pose_reduce(
    const float* __restrict__ part, float* __restrict__ out)
{
    __shared__ float red[4][6];
    const int tid = threadIdx.x;
    float a[6];
    #pragma unroll
    for (int k = 0; k < 6; ++k) {
        float s = 0.f;
        for (int i = tid; i < NBLK; i += 256) s += part[k * NBLK + i];
        a[k] = s;
    }
    #pragma unroll
    for (int k = 0; k < 6; ++k)
        #pragma unroll
        for (int off = 32; off > 0; off >>= 1)
            a[k] += __shfl_down(a[k], off, 64);

    const int wid = tid >> 6, lane = tid & 63;
    if (lane == 0) {
        #pragma unroll
        for (int k = 0; k < 6; ++k) red[wid][k] = a[k];
    }
    __syncthreads();
    if (tid == 0) {
        float t[6];
        #pragma unroll
        for (int k = 0; k < 6; ++k) t[k] = red[0][k] + red[1][k] + red[2][k] + red[3][k];
        const float bone = t[0] * (1.f / ((float)TOTAL * 49.f));
        const float ang  = t[1] * (1.f / ((float)TOTAL * 4.f));
        const float sym  = t[2] * (1.f / ((float)TOTAL * 24.f));
        const float temporal = t[4] * (1.f / ((float)B_ * (float)(S_ - 2) * 50.f))
                             + 0.5f * t[3] * (1.f / ((float)B_ * (float)(S_ - 1) * 50.f));
        const float sup  = t[5] * (1.f / ((float)TOTAL * 49.f));
        out[0] = bone;
        out[1] = ang;
        out[2] = sym;
        out[3] = temporal;
        out[4] = sup;
        out[5] = bone + 0.5f * ang + 0.3f * sym + 0.2f * temporal + sup;
    }
}

extern "C" void kernel_launch(void* const* d_in, const int* in_sizes, int n_in,
                              void* d_out, int out_size, void* d_ws, size_t ws_size,
                              hipStream_t stream)
{
    const float* pred = (const float*)d_in[0];
    const float* tgt  = (const float*)d_in[1];
    float* part = (float*)d_ws;   // 6 * 2048 f32 = 48 KB (SoA)
    pose_main<<<NBLK, TPB, 0, stream>>>(pred, tgt, part);
    pose_reduce<<<1, 256, 0, stream>>>(part, (float*)d_out);
}

// Round 5
// 43.784 us; speedup vs baseline: 2.2515x; 2.2515x over previous
//
#include <hip/hip_runtime.h>
#include <math.h>

#define TPB 256
#define CH  16            // samples per chunk
#define CPB 8             // chunks per block

static constexpr int B_     = 64;
static constexpr int S_     = 2048;
static constexpr int TOTAL  = B_ * S_;          // 131072 samples
static constexpr int NCHUNK = TOTAL / CH;       // 8192
static constexpr int NBLK   = NCHUNK / CPB;     // 1024 blocks = 4/CU exactly
static constexpr int SAMPB  = 600;              // bytes per sample (150 f32)
static constexpr int PREDB  = (CH + 2) * SAMPB; // 10800 B pred incl. 2-sample halo
static constexpr int TGTB   = CH * SAMPB;       // 9600 B tgt
static constexpr int CHB    = PREDB + TGTB;     // 20400 B staged per chunk
static constexpr int BUFB   = 20480;            // LDS buffer stride (5*4096, slack for tail lanes)
static constexpr long TOTB  = (long)TOTAL * SAMPB;

// ---- union bone table: 51 edges covers bone-set(49) + conn-set(49) ----
// k=9,10 conn-only -> sentinel ranges; k=7,8 bone-only -> wsup=0.
// k>=11 (hand edges): min=0.01, max=0.08, wsup=1 computed in code.
__constant__ int US_[51] = {0,1,1,2,3,5,6,4,7,7,4,
    8,8,8,8,8,9,10,11,13,14,
    15,17,18,19,21,22,23,25,26,27,
    29,29,29,29,29,30,31,32,34,35,
    36,38,39,40,42,43,44,46,47,48};
__constant__ int UE_[51] = {1,2,5,3,4,6,7,8,29,8,29,
    9,13,17,21,25,10,11,12,14,15,
    16,18,19,20,22,23,24,26,27,28,
    30,34,38,42,46,31,32,33,35,36,
    37,39,40,41,43,44,45,47,48,49};
__constant__ float UMIN11_[11] = {0.05f,0.1f,0.1f,0.2f,0.2f,0.2f,0.2f,0.05f,0.05f,-1e9f,-1e9f};
__constant__ float UMAX11_[11] = {0.15f,0.2f,0.2f,0.35f,0.35f,0.35f,0.35f,0.15f,0.15f,1e9f,1e9f};
__constant__ float WSUP11_[11] = {1.f,1.f,1.f,1.f,1.f,1.f,1.f,0.f,0.f,1.f,1.f};
__constant__ int SL_[24] = {8,9,10,11,12,13,14,15,16,17,18,19,20,21,22,23,24,25,26,27,28,2,3,4};
__constant__ int SR_[24] = {29,30,31,32,33,34,35,36,37,38,39,40,41,42,43,44,45,46,47,48,49,5,6,7};
__constant__ int AJ_[4] = {1,1,2,5};
__constant__ int BJ_[4] = {2,5,3,6};
__constant__ int CJ_[4] = {3,6,4,7};

struct F3 { float x, y, z; };
__device__ __forceinline__ F3 ld3(const float* p) { return *(const F3*)p; }

typedef const __attribute__((address_space(1))) void* gas_t;
typedef __attribute__((address_space(3))) void* las_t;

__global__ __launch_bounds__(TPB, 4) void pose_main(
    const float* __restrict__ pred, const float* __restrict__ tgt,
    float* __restrict__ part)
{
    __shared__ __align__(16) char LDS[2 * BUFB];   // 40960 B -> 4 blocks/CU

    const int tid = threadIdx.x;
    const int blk = blockIdx.x;
    const int li  = tid & 15;
    const int g   = tid >> 4;
    const int jb  = li * 150;

    // ================= hoisted per-thread constants =================
    int   uS[3], uE[3];
    float uMn[3], uMx[3], uW[3];
    #pragma unroll
    for (int s = 0; s < 3; ++s) {
        const int k = g + 16 * s;
        uS[s] = jb + US_[k] * 3;  uE[s] = jb + UE_[k] * 3;
        uMn[s] = (k < 11) ? UMIN11_[k] : 0.01f;
        uMx[s] = (k < 11) ? UMAX11_[k] : 0.08f;
        uW[s]  = (k < 11) ? WSUP11_[k] : 1.f;
    }
    // extra union slot on wave3 (g=12,13,14 -> k=48,49,50; g=15 neutral)
    const int t3 = g - 12;
    const int ke = 48 + (t3 < 0 ? 0 : (t3 > 2 ? 2 : t3));
    const bool e_on = (g >= 12 && g < 15);
    const int   eS = jb + US_[ke] * 3, eE = jb + UE_[ke] * 3;
    const float eMn = e_on ? 0.01f : -1e9f;
    const float eMx = e_on ? 0.08f :  1e9f;
    const float eW  = e_on ? 1.f   :  0.f;
    // symmetry: slot0 k=g (all); slot1 k=16+(g-4) on waves 1,2
    const int s0L = jb + SL_[g] * 3, s0R = jb + SR_[g] * 3;
    const int k1  = 16 + ((g - 4) & 7);
    const int s1L = jb + SL_[k1] * 3, s1R = jb + SR_[k1] * 3;
    // angle: wave0, k = g (0..3)
    const int aA = jb + AJ_[g & 3] * 3, aB = jb + BJ_[g & 3] * 3, aC = jb + CJ_[g & 3] * 3;
    // temporal: base j = g; wave1 extra j=48,49
    const int tb0 = jb + 3 * g;
    const int jx  = 48 + ((g - 4) & 1);
    const int tbx = jb + 3 * (jx > 49 ? 49 : jx);
    const bool tex_on = (g == 4 || g == 5);

    float a_bone = 0.f, a_ang = 0.f, a_sym = 0.f, a_vel = 0.f, a_acc = 0.f, a_sup = 0.f;

    // ================= async HBM->LDS staging (zero VGPR) =================
    auto stage = [&](int cidx, char* lbuf) {
        const long nb = (long)cidx * TGTB;
        const char* pb = (const char*)pred + nb;
        const char* tb = (const char*)tgt  + nb - PREDB;
        const long prem = TOTB - nb - 16;        // clamp pred halo at buffer end
        char* wdst = lbuf + ((tid >> 6) << 10);  // wave-uniform LDS base
        #pragma unroll
        for (int s = 0; s < 5; ++s) {
            const long o = (long)tid * 16 + s * 4096;
            const char* src = (o < PREDB)
                ? pb + (o > prem ? prem : o)
                : tb + (o > (long)(CHB - 16) ? (long)(CHB - 16) : o);
            __builtin_amdgcn_global_load_lds((gas_t)src, (las_t)(wdst + s * 4096), 16, 0, 0);
        }
    };

    const int c0 = blk * CPB;
    stage(c0, LDS);                  // prologue: chunk 0 -> buf0 (5 loads in flight)

    #pragma unroll
    for (int c = 0; c < CPB; ++c) {
        char* curb = LDS + (c & 1) * BUFB;
        char* nxtb = LDS + ((c & 1) ^ 1) * BUFB;
        if (c + 1 < CPB) {
            stage(c0 + c + 1, nxtb);                       // +5 -> 10 outstanding
            asm volatile("s_waitcnt vmcnt(5)" ::: "memory"); // cur's 5 landed
        } else {
            asm volatile("s_waitcnt vmcnt(0)" ::: "memory");
        }
        __builtin_amdgcn_s_barrier();        // everyone's cur loads landed
        __builtin_amdgcn_sched_barrier(0);   // no ds_read hoisted above this

        const float* Jl = (const float*)curb;
        const float* Tl = Jl + PREDB / 4;
        const int cidx = c0 + c;

        // ---------- union: bone penalty + supervised ----------
        #pragma unroll
        for (int s = 0; s < 3; ++s) {
            const F3 je = ld3(Jl + uE[s]), js = ld3(Jl + uS[s]);
            const float dx = je.x - js.x, dy = je.y - js.y, dz = je.z - js.z;
            const float pb = sqrtf(dx * dx + dy * dy + dz * dz);
            a_bone += fmaxf(pb - uMx[s], 0.f) + fmaxf(uMn[s] - pb, 0.f);
            const F3 te = ld3(Tl + uE[s]), ts = ld3(Tl + uS[s]);
            const float tx = te.x - ts.x, ty = te.y - ts.y, tz = te.z - ts.z;
            const float tb = sqrtf(tx * tx + ty * ty + tz * tz);
            a_sup += uW[s] * fabsf(pb - tb);
        }
        if (tid >= 192) {   // wave3: union extra k=48..50
            const F3 je = ld3(Jl + eE), js = ld3(Jl + eS);
            const float dx = je.x - js.x, dy = je.y - js.y, dz = je.z - js.z;
            const float pb = sqrtf(dx * dx + dy * dy + dz * dz);
            a_bone += fmaxf(pb - eMx, 0.f) + fmaxf(eMn - pb, 0.f);
            const F3 te = ld3(Tl + eE), ts = ld3(Tl + eS);
            const float tx = te.x - ts.x, ty = te.y - ts.y, tz = te.z - ts.z;
            const float tb = sqrtf(tx * tx + ty * ty + tz * tz);
            a_sup += eW * fabsf(pb - tb);
        }

        // ---------- symmetry ----------
        {
            const F3 L = ld3(Jl + s0L), R = ld3(Jl + s0R);
            a_sym += fabsf(L.x + R.x) + 0.5f * (fabsf(L.y - R.y) + fabsf(L.z - R.z));
        }
        if (tid >= 64 && tid < 192) {   // waves 1,2: sym k=16..23
            const F3 L = ld3(Jl + s1L), R = ld3(Jl + s1R);
            a_sym += fabsf(L.x + R.x) + 0.5f * (fabsf(L.y - R.y) + fabsf(L.z - R.z));
        }

        // ---------- angles (wave0 only) ----------
        if (tid < 64) {
            const F3 A = ld3(Jl + aA), Bb = ld3(Jl + aB), C = ld3(Jl + aC);
            const float v1x = A.x - Bb.x, v1y = A.y - Bb.y, v1z = A.z - Bb.z;
            const float v2x = C.x - Bb.x, v2y = C.y - Bb.y, v2z = C.z - Bb.z;
            const float n12 = (v1x*v1x + v1y*v1y + v1z*v1z) * (v2x*v2x + v2y*v2y + v2z*v2z);
            const float inv = __frsqrt_rn(fmaxf(n12, 1e-24f));
            float cosv = (v1x*v2x + v1y*v2y + v1z*v2z) * inv;
            cosv = fminf(fmaxf(cosv, -1.f), 1.f);
            const float deg = acosf(cosv) * 57.29577951308232f;
            a_ang += fmaxf(30.f - deg, 0.f) + fmaxf(deg - 150.f, 0.f);
        }

        // ---------- temporal ----------
        {
            const int sidx = ((cidx * CH) & (S_ - 1)) + li;
            const bool v_ok = sidx < S_ - 1;
            const bool a_ok = sidx < S_ - 2;
            const float* tp = Jl + tb0;
            #pragma unroll
            for (int s = 0; s < 3; ++s) {
                const F3 p0 = ld3(tp + 48*s), p1 = ld3(tp + 48*s + 150), p2 = ld3(tp + 48*s + 300);
                if (v_ok) {
                    const float vx = p1.x - p0.x, vy = p1.y - p0.y, vz = p1.z - p0.z;
                    a_vel += sqrtf(vx*vx + vy*vy + vz*vz);
                    if (a_ok) {
                        const float ax = p2.x - 2.f*p1.x + p0.x;
                        const float ay = p2.y - 2.f*p1.y + p0.y;
                        const float az = p2.z - 2.f*p1.z + p0.z;
                        a_acc += sqrtf(ax*ax + ay*ay + az*az);
                    }
                }
            }
            if (tid >= 64 && tid < 128) {   // wave1 extra j=48,49
                const float* tq = Jl + tbx;
                const F3 p0 = ld3(tq), p1 = ld3(tq + 150), p2 = ld3(tq + 300);
                if (tex_on && v_ok) {
                    const float vx = p1.x - p0.x, vy = p1.y - p0.y, vz = p1.z - p0.z;
                    a_vel += sqrtf(vx*vx + vy*vy + vz*vz);
                    if (a_ok) {
                        const float ax = p2.x - 2.f*p1.x + p0.x;
                        const float ay = p2.y - 2.f*p1.y + p0.y;
                        const float az = p2.z - 2.f*p1.z + p0.z;
                        a_acc += sqrtf(ax*ax + ay*ay + az*az);
                    }
                }
            }
        }

        asm volatile("" ::: "memory");   // block LDS-load CSE across chunk iterations
        __builtin_amdgcn_s_barrier();    // all done reading curb before it is restaged
    }

    // ================= block reduction =================
    float vals[6] = {a_bone, a_ang, a_sym, a_vel, a_acc, a_sup};
    #pragma unroll
    for (int k = 0; k < 6; ++k)
        #pragma unroll
        for (int off = 32; off > 0; off >>= 1)
            vals[k] += __shfl_down(vals[k], off, 64);

    float* red = (float*)LDS;            // reuse staging LDS (last barrier passed)
    const int wid = tid >> 6, lane = tid & 63;
    if (lane == 0) {
        #pragma unroll
        for (int k = 0; k < 6; ++k) red[wid * 6 + k] = vals[k];
    }
    __syncthreads();
    if (tid == 0) {
        #pragma unroll
        for (int k = 0; k < 6; ++k)     // SoA partials: part[k][blk]
            part[k * NBLK + blk] = red[k] + red[6 + k] + red[12 + k] + red[18 + k];
    }
}

__global__ __launch_bounds__(256) void pose_reduce(
    const float* __restrict__ part, float* __restrict__ out)
{
    __shared__ float red[4][6];
    const int tid = threadIdx.x;
    float a[6];
    #pragma unroll
    for (int k = 0; k < 6; ++k) {
        float s = 0.f;
        for (int i = tid; i < NBLK; i += 256) s += part[k * NBLK + i];
        a[k] = s;
    }
    #pragma unroll
    for (int k = 0; k < 6; ++k)
        #pragma unroll
        for (int off = 32; off > 0; off >>= 1)
            a[k] += __shfl_down(a[k], off, 64);

    const int wid = tid >> 6, lane = tid & 63;
    if (lane == 0) {
        #pragma unroll
        for (int k = 0; k < 6; ++k) red[wid][k] = a[k];
    }
    __syncthreads();
    if (tid == 0) {
        float t[6];
        #pragma unroll
        for (int k = 0; k < 6; ++k) t[k] = red[0][k] + red[1][k] + red[2][k] + red[3][k];
        const float bone = t[0] * (1.f / ((float)TOTAL * 49.f));
        const float ang  = t[1] * (1.f / ((float)TOTAL * 4.f));
        const float sym  = t[2] * (1.f / ((float)TOTAL * 24.f));
        const float temporal = t[4] * (1.f / ((float)B_ * (float)(S_ - 2) * 50.f))
                             + 0.5f * t[3] * (1.f / ((float)B_ * (float)(S_ - 1) * 50.f));
        const float sup  = t[5] * (1.f / ((float)TOTAL * 49.f));
        out[0] = bone;
        out[1] = ang;
        out[2] = sym;
        out[3] = temporal;
        out[4] = sup;
        out[5] = bone + 0.5f * ang + 0.3f * sym + 0.2f * temporal + sup;
    }
}

extern "C" void kernel_launch(void* const* d_in, const int* in_sizes, int n_in,
                              void* d_out, int out_size, void* d_ws, size_t ws_size,
                              hipStream_t stream)
{
    const float* pred = (const float*)d_in[0];
    const float* tgt  = (const float*)d_in[1];
    float* part = (float*)d_ws;   // 6 * 1024 f32 = 24 KB (SoA)
    pose_main<<<NBLK, TPB, 0, stream>>>(pred, tgt, part);
    pose_reduce<<<1, 256, 0, stream>>>(part, (float*)d_out);
}